// Round 4
// baseline (118355.164 us; speedup 1.0000x reference)
//
#include <hip/hip_runtime.h>
#include <math.h>

// Tobit Kalman filter with LSTM dynamics, T=512 sequential steps.
// 256 persistent blocks x 256 threads (1/CU). LSTM weights in registers
// (each block owns 16 m-rows + 32 f/q-rows + Wfc slices). Block 0 is ALSO the
// "Kalman block": M, GJ workspace, Yt live in its LDS (93KB pool); P (64KB)
// lives in ws (global, L2-resident, only block 0 touches it after init).
// 4 grid barriers per step:
//  bar0 -> alpha: m-gates -> publish hy
//  bar1 -> beta : b<128 yraw row | b>=128 Whh_m@hy dots (regs)
//  bar2 -> gamma: f/q gates -> publish hF/hQ; Fv/Qv partials -> slab;
//                 b<128 Whh_m dots; block0: z=H@yraw + tobit stats
//  bar3 -> eps  : all: Whh_f/q@h dots; block0: Fv/Qv reduce, Ht stage,
//                 M=(FPF+Q)H^T, R2, in-place GJ inverse, t1, Yt, MP, P-update,
//                 y-finalize -> publish y, out[t]

#define TT   512
#define NOBS 64
#define NHID 1024
#define NSTA 128
#define NBLK 256
#define NTHR 256

// ---- LDS pool layout (floats). Only block 0 uses offsets >= 1280. ----
#define L_HL    0        // 1024 : h broadcast (256 float4)
#define L_YL    1024     // 128  : y / yraw broadcast (yraw persists gamma->eps)
#define L_GL    1152     // 64   : gate pre-activations / reduce scratch
#define L_HLOC  1216     // 8(+pad): this block's 8 f/q h-values
#define L_M     1280     // 8192 : M = Pp H^T [128][64]  (later MP)
#define L_A     9472     // 4352 : GJ matrix [64][68] -> inverse
#define L_U     13824    // 8704 : Ht[128][64] (M,R2) / Yt[128][68] (later)
#define L_FV    22528    // 128
#define L_QV    22656    // 128
#define L_PP    22784    // 64   : tobit p
#define L_RM    22848    // 64
#define L_DD    22912    // 64   : innovation
#define L_T1    22976    // 64
#define L_FCOL  23040    // 64
#define L_PROW  23104    // 68
#define L_PIV   23172    // 1
#define POOLSZ  23184    // 92736 bytes (proven envelope: <=128KB static LDS)

// ---- ws layout (floats) ----
#define W_BAR   0        // 2048 (8KB barrier region)
#define W_HY    2048     // 1024
#define W_HF    3072     // 1024
#define W_HQ    4096     // 1024
#define W_YRAW  5120     // 128
#define W_Y     5248     // 128
#define W_PF    5376     // 16384 : Fv partial slab [128 blocks][128]
#define W_PQ    21760    // 16384 : Qv partial slab
#define W_P     38144    // 16384 : covariance P [128][128] (block 0 only)

__device__ __forceinline__ float sigm(float v) { return 1.0f / (1.0f + expf(-v)); }

__device__ __forceinline__ float rsum4 (float s){ s+=__shfl_xor(s,2); s+=__shfl_xor(s,1); return s; }
__device__ __forceinline__ float rsum16(float s){ s+=__shfl_xor(s,8); s+=__shfl_xor(s,4); s+=__shfl_xor(s,2); s+=__shfl_xor(s,1); return s; }
__device__ __forceinline__ float rsum64(float s){
  s+=__shfl_xor(s,32); s+=__shfl_xor(s,16); s+=__shfl_xor(s,8);
  s+=__shfl_xor(s,4);  s+=__shfl_xor(s,2);  s+=__shfl_xor(s,1); return s;
}

// Two-level grid barrier (hierarchical arrival + release). Counters zeroed by
// hipMemsetAsync. 256 blocks -> 8 leaves x 32. Proven in rounds 1-2.
__device__ __forceinline__ void gsync(unsigned* bar) {
  __syncthreads();
  if (threadIdx.x == 0) {
    __builtin_amdgcn_fence(__ATOMIC_RELEASE, "agent");
    unsigned* leafc = bar + (blockIdx.x & 7) * 64;
    unsigned* rootc = bar + 512;
    unsigned* rootg = bar + 576;
    unsigned* leaff = bar + 640 + (blockIdx.x & 7) * 64;
    unsigned g = __hip_atomic_load(rootg, __ATOMIC_RELAXED, __HIP_MEMORY_SCOPE_AGENT);
    unsigned a = __hip_atomic_fetch_add(leafc, 1u, __ATOMIC_ACQ_REL, __HIP_MEMORY_SCOPE_AGENT);
    if (a == 31u) {
      __hip_atomic_store(leafc, 0u, __ATOMIC_RELAXED, __HIP_MEMORY_SCOPE_AGENT);
      unsigned r = __hip_atomic_fetch_add(rootc, 1u, __ATOMIC_ACQ_REL, __HIP_MEMORY_SCOPE_AGENT);
      if (r == 7u) {
        __hip_atomic_store(rootc, 0u, __ATOMIC_RELAXED, __HIP_MEMORY_SCOPE_AGENT);
        __hip_atomic_store(rootg, g + 1u, __ATOMIC_RELEASE, __HIP_MEMORY_SCOPE_AGENT);
      } else {
        while (__hip_atomic_load(rootg, __ATOMIC_RELAXED, __HIP_MEMORY_SCOPE_AGENT) == g)
          __builtin_amdgcn_s_sleep(1);
      }
      __hip_atomic_store(leaff, g + 1u, __ATOMIC_RELEASE, __HIP_MEMORY_SCOPE_AGENT);
    } else {
      while (__hip_atomic_load(leaff, __ATOMIC_RELAXED, __HIP_MEMORY_SCOPE_AGENT) == g)
        __builtin_amdgcn_s_sleep(1);
    }
    __builtin_amdgcn_fence(__ATOMIC_ACQUIRE, "agent");
  }
  __syncthreads();
}

#define DOT16P(RES, W, HP) do { float s_ = 0.f; \
  _Pragma("unroll") for (int c_ = 0; c_ < 16; ++c_) { float4 h_ = (HP)[c_*16 + ln]; \
    s_ += W[c_].x*h_.x + W[c_].y*h_.y + W[c_].z*h_.z + W[c_].w*h_.w; } RES = s_; } while (0)
#define DOT2P(RES, W, YP) do { float s_ = 0.f; \
  _Pragma("unroll") for (int c_ = 0; c_ < 2; ++c_) { float4 h_ = (YP)[c_*16 + ln]; \
    s_ += W[c_].x*h_.x + W[c_].y*h_.y + W[c_].z*h_.z + W[c_].w*h_.w; } RES = s_; } while (0)

__global__ void __launch_bounds__(NTHR, 1)
tobit_main(const float* __restrict__ x,   const float* __restrict__ y0,
           const float* __restrict__ P0,  const float* __restrict__ H,
           const float* __restrict__ R,   const float* __restrict__ Tl,
           const float* __restrict__ Tu,
           const float* __restrict__ Wih_m, const float* __restrict__ Whh_m,
           const float* __restrict__ bih_m, const float* __restrict__ bhh_m,
           const float* __restrict__ Wfc_m, const float* __restrict__ bfc_m,
           const float* __restrict__ Wih_f, const float* __restrict__ Whh_f,
           const float* __restrict__ bih_f, const float* __restrict__ bhh_f,
           const float* __restrict__ Wfc_f, const float* __restrict__ bfc_f,
           const float* __restrict__ Wih_q, const float* __restrict__ Whh_q,
           const float* __restrict__ bih_q, const float* __restrict__ bhh_q,
           const float* __restrict__ Wfc_q, const float* __restrict__ bfc_q,
           float* __restrict__ out, float* __restrict__ ws)
{
  const int b   = blockIdx.x;
  const int tid = threadIdx.x;
  const int w   = tid >> 4;     // team 0..15
  const int ln  = tid & 15;     // lane in team
  unsigned* bar = (unsigned*)ws;

  __shared__ __attribute__((aligned(16))) float pool[POOLSZ];
  float4* hl4 = (float4*)pool;
  float4* yl4 = (float4*)(pool + L_YL);
  float*  gl  = pool + L_GL;
  float*  hloc= pool + L_HLOC;

  // ---- ownership & persistent register weights ----
  const int  bb  = b & 127;
  const bool isF = (b < 128);
  const float* WhhX = isF ? Whh_f : Whh_q;
  const float* WihX = isF ? Wih_f : Wih_q;
  const float* bihX = isF ? bih_f : bih_q;
  const float* bhhX = isF ? bhh_f : bhh_q;

  const int r_m  = (w >> 2) * NHID + b * 4 + (w & 3);
  const int idx0 = w * 2, idx1 = w * 2 + 1;
  const int r_f0 = (idx0 >> 3) * NHID + bb * 8 + (idx0 & 7);
  const int r_f1 = (idx1 >> 3) * NHID + bb * 8 + (idx1 & 7);

  float4 wm[16], wf0[16], wf1[16], im[2], if0v[2], if1v[2];
  #pragma unroll
  for (int c = 0; c < 16; ++c) {
    wm[c]  = *(const float4*)(Whh_m + (size_t)r_m  * NHID + (c*16 + ln) * 4);
    wf0[c] = *(const float4*)(WhhX  + (size_t)r_f0 * NHID + (c*16 + ln) * 4);
    wf1[c] = *(const float4*)(WhhX  + (size_t)r_f1 * NHID + (c*16 + ln) * 4);
  }
  #pragma unroll
  for (int c = 0; c < 2; ++c) {
    im[c]   = *(const float4*)(Wih_m + (size_t)r_m  * NSTA + (c*16 + ln) * 4);
    if0v[c] = *(const float4*)(WihX  + (size_t)r_f0 * NSTA + (c*16 + ln) * 4);
    if1v[c] = *(const float4*)(WihX  + (size_t)r_f1 * NSTA + (c*16 + ln) * 4);
  }
  const float bm_b  = bih_m[r_m]  + bhh_m[r_m];
  const float bf0_b = bihX[r_f0] + bhhX[r_f0];
  const float bf1_b = bihX[r_f1] + bhhX[r_f1];
  // Wfc_m row (blocks 0..127 own yraw[b]): 4 floats/thread
  float4 wfcm4 = make_float4(0.f,0.f,0.f,0.f);
  if (b < NSTA) wfcm4 = *(const float4*)(Wfc_m + (size_t)b * NHID + tid * 4);
  // Wfc_f/q column slice (8 cols of this block's units): 4 floats/thread
  float4 wfc4 = *(const float4*)((isF ? Wfc_f : Wfc_q) + (size_t)(tid >> 1) * NHID + bb * 8 + (tid & 1) * 4);

  float hm_r = 0.f, hf0_r = 0.f, hf1_r = 0.f;
  float cm = 0.f, cf = 0.f;

  // ---- init: cooperative P0 -> ws (ordered before eps by bar0..bar3) ----
  {
    float4* Pg4 = (float4*)(ws + W_P);
    const float4* P04 = (const float4*)P0;
    if (tid < 16) Pg4[b * 16 + tid] = P04[b * 16 + tid];
  }

  for (int t = 0; t < TT; ++t) {
    // ================= alpha: m-gates =================
    {
      const float4* src = (t == 0) ? (const float4*)y0 : (const float4*)(ws + W_Y);
      if (tid < 32) yl4[tid] = src[tid];
    }
    __syncthreads();
    {
      float s; DOT2P(s, im, yl4);
      s = rsum16(s) + hm_r + bm_b;
      if (ln == 0) gl[w] = s;
    }
    __syncthreads();
    if (tid < 4) {
      float gi = sigm(gl[tid]),      gf = sigm(gl[4 + tid]);
      float gg = tanhf(gl[8 + tid]), go = sigm(gl[12 + tid]);
      cm = gf * cm + gi * gg;
      ws[W_HY + b * 4 + tid] = go * tanhf(cm);
    }
    gsync(bar);

    // ================= beta: yraw | wm-dots =================
    if (b < NSTA) {
      float4 hv = ((const float4*)(ws + W_HY))[tid];
      float s = wfcm4.x*hv.x + wfcm4.y*hv.y + wfcm4.z*hv.z + wfcm4.w*hv.w;
      s = rsum64(s);
      if ((tid & 63) == 0) gl[tid >> 6] = s;
      __syncthreads();
      if (tid == 0) ws[W_YRAW + b] = gl[0] + gl[1] + gl[2] + gl[3] + bfc_m[b];
    } else {
      hl4[tid] = ((const float4*)(ws + W_HY))[tid];
      __syncthreads();
      float s; DOT16P(s, wm, hl4); hm_r = rsum16(s);
    }
    gsync(bar);

    // ================= gamma: f/q gates + partials + dots + tobit =================
    if (tid < 32) yl4[tid] = ((const float4*)(ws + W_YRAW))[tid];   // yraw -> LDS (persists into eps)
    __syncthreads();
    {
      float s0, s1; DOT2P(s0, if0v, yl4); DOT2P(s1, if1v, yl4);
      s0 = rsum16(s0) + hf0_r + bf0_b;
      s1 = rsum16(s1) + hf1_r + bf1_b;
      if (ln == 0) { gl[idx0] = s0; gl[idx1] = s1; }
    }
    __syncthreads();
    if (tid < 8) {
      float gi = sigm(gl[tid]),       gf = sigm(gl[8 + tid]);
      float gg = tanhf(gl[16 + tid]), go = sigm(gl[24 + tid]);
      cf = gf * cf + gi * gg;
      float hv = go * tanhf(cf);
      hloc[tid] = hv;
      ws[(isF ? W_HF : W_HQ) + bb * 8 + tid] = hv;
    }
    __syncthreads();
    { // Fv/Qv partial: this block's 8 h-values x Wfc columns
      int j = tid >> 1, uo = (tid & 1) * 4;
      float s = wfc4.x*hloc[uo] + wfc4.y*hloc[uo+1] + wfc4.z*hloc[uo+2] + wfc4.w*hloc[uo+3];
      s += __shfl_xor(s, 1);
      if ((tid & 1) == 0) ws[(isF ? W_PF : W_PQ) + bb * 128 + j] = s;
    }
    if (b < NSTA) { // wm-dots (blocks >=128 did them in beta)
      hl4[tid] = ((const float4*)(ws + W_HY))[tid];
      __syncthreads();
      float s; DOT16P(s, wm, hl4); hm_r = rsum16(s);
    }
    if (b == 0) { // z = H @ yraw + tobit scalar stats (yraw in yl4)
      int j = tid >> 2, l4 = tid & 3;
      float s = 0.f;
      const float4* hrow = (const float4*)(H + (size_t)j * NSTA);
      #pragma unroll
      for (int c = 0; c < 8; ++c) {
        float4 h4 = hrow[l4 * 8 + c];
        float4 y4 = *(float4*)&pool[L_YL + (l4 * 8 + c) * 4];
        s += h4.x*y4.x + h4.y*y4.y + h4.z*y4.z + h4.w*y4.w;
      }
      s = rsum4(s);
      if (l4 == 0) {
        float z   = s;
        float Rii = R[j * 64 + j];
        float r_  = sqrtf(Rii) + 1e-4f;
        float zl  = (Tl[j] - z) / r_;
        float zu  = (Tu[j] - z) / r_;
        const float ISQ2 = 0.70710678118654752f;
        const float IPDF = 0.3989422804014327f;
        float cpl = 0.5f * (1.f + erff(zl * ISQ2));
        float cpu = 0.5f * (1.f + erff(zu * ISQ2));
        float ppl = IPDF * expf(-0.5f * zl * zl);
        float ppu = IPDF * expf(-0.5f * zu * zu);
        float p   = cpu - cpl + 1e-4f;
        float l   = (ppu - ppl) / p;
        float c   = zl*ppl - zu*ppu;
        float Ey  = p * (z - r_*l) + cpl*Tl[j] + (1.f - cpu)*Tu[j];
        pool[L_PP + j] = p;
        pool[L_RM + j] = Rii * (c/p + 1.f - l*l);
        pool[L_DD + j] = x[(size_t)t*NOBS + j] - Ey;
      }
    }
    gsync(bar);

    // ================= eps: wf-dots (all) + Kalman (block 0) =================
    hl4[tid] = ((const float4*)(ws + (isF ? W_HF : W_HQ)))[tid];
    __syncthreads();
    {
      float s;
      DOT16P(s, wf0, hl4); hf0_r = rsum16(s);
      DOT16P(s, wf1, hl4); hf1_r = rsum16(s);
    }

    if (b == 0) {
      float* Pg  = ws + W_P;          // global covariance (block 0 private)
      float* Mr_ = pool + L_M;
      float* A_  = pool + L_A;
      float* U_  = pool + L_U;        // Ht (stride 64) then Yt (stride 68)
      float* Fv_ = pool + L_FV;  float* Qv_ = pool + L_QV;
      float* pp_ = pool + L_PP;  float* rm_ = pool + L_RM;
      float* dd_ = pool + L_DD;  float* t1_ = pool + L_T1;

      // ---- Fv/Qv reduce (coalesced column sums of the slabs) ----
      {
        int j = tid & 127;
        const float* slab = ws + ((tid < 128) ? W_PF : W_PQ);
        float s = 0.f;
        #pragma unroll 4
        for (int bbk = 0; bbk < 128; ++bbk) s += slab[bbk * 128 + j];
        s += (tid < 128) ? bfc_f[j] : bfc_q[j];
        ((tid < 128) ? Fv_ : Qv_)[j] = s;
      }
      // ---- Ht stage: Ht[k][j] = H[j][k] ----
      {
        const float4* H4 = (const float4*)H;
        #pragma unroll
        for (int i = 0; i < 8; ++i) {
          int e4 = tid + i * NTHR;            // 2048 float4s
          float4 h4 = H4[e4];
          int f = e4 * 4, j = f >> 7, k = f & 127;
          U_[(k+0)*64 + j] = h4.x; U_[(k+1)*64 + j] = h4.y;
          U_[(k+2)*64 + j] = h4.z; U_[(k+3)*64 + j] = h4.w;
        }
      }
      __syncthreads();

      // ---- M[k][j] = Fv_k * sum_m P[k][m]*Fv_m*Ht[m][j] + Qv_k*Ht[k][j] ----
      {
        int wv = tid >> 6, lj = tid & 63;
        #pragma unroll
        for (int g = 0; g < 4; ++g) {
          int k0 = wv * 32 + g * 8;
          float acc[8];
          #pragma unroll
          for (int kk = 0; kk < 8; ++kk) acc[kk] = 0.f;
          #pragma unroll 2
          for (int mq = 0; mq < 32; ++mq) {
            float4 fv4 = *(float4*)&Fv_[mq * 4];
            float ht0 = U_[(mq*4+0)*64 + lj], ht1 = U_[(mq*4+1)*64 + lj];
            float ht2 = U_[(mq*4+2)*64 + lj], ht3 = U_[(mq*4+3)*64 + lj];
            #pragma unroll
            for (int kk = 0; kk < 8; ++kk) {
              float4 pr = *(const float4*)&Pg[(k0+kk)*NSTA + mq*4];   // wave-uniform -> broadcast
              acc[kk] += (pr.x*fv4.x)*ht0 + (pr.y*fv4.y)*ht1
                       + (pr.z*fv4.z)*ht2 + (pr.w*fv4.w)*ht3;
            }
          }
          #pragma unroll
          for (int kk = 0; kk < 8; ++kk) {
            int k = k0 + kk;
            Mr_[k*64 + lj] = Fv_[k]*acc[kk] + Qv_[k]*U_[k*64 + lj];
          }
        }
      }
      __syncthreads();

      // ---- R2 -> A: A[i][j] = p_i p_j sum_k Ht[k][i] M[k][j] + diag(rm) ----
      {
        int i = tid & 63, wv = tid >> 6;
        #pragma unroll
        for (int jt = 0; jt < 2; ++jt) {
          int jb = wv * 16 + jt * 8;
          float acc[8];
          #pragma unroll
          for (int jj = 0; jj < 8; ++jj) acc[jj] = 0.f;
          #pragma unroll 2
          for (int k = 0; k < 128; ++k) {
            float hti = U_[k*64 + i];
            float4 m0 = *(float4*)&Mr_[k*64 + jb];
            float4 m1 = *(float4*)&Mr_[k*64 + jb + 4];
            acc[0] += hti*m0.x; acc[1] += hti*m0.y; acc[2] += hti*m0.z; acc[3] += hti*m0.w;
            acc[4] += hti*m1.x; acc[5] += hti*m1.y; acc[6] += hti*m1.z; acc[7] += hti*m1.w;
          }
          #pragma unroll
          for (int jj = 0; jj < 8; ++jj) {
            int j = jb + jj;
            A_[i*68 + j] = pp_[i]*pp_[j]*acc[jj] + ((i == j) ? rm_[i] : 0.f);
          }
        }
      }
      __syncthreads();

      // ---- in-place Gauss-Jordan inverse of A (64x64, SPD, no pivoting) ----
      {
        float* fcol = pool + L_FCOL;
        float* prow = pool + L_PROW;
        for (int kp = 0; kp < 64; ++kp) {
          if (tid < 64) fcol[tid] = A_[tid*68 + kp];
          else if (tid < 128) prow[tid - 64] = A_[kp*68 + (tid - 64)];
          else if (tid == 128) pool[L_PIV] = 1.0f / A_[kp*68 + kp];
          __syncthreads();
          float pv = pool[L_PIV];
          int i = tid & 63, jb = (tid >> 6) * 16;
          float fp = fcol[i] * pv;
          bool pr = (i == kp);
          #pragma unroll
          for (int l = 0; l < 4; ++l) {
            int j0 = jb + l * 4;
            float4 a4 = *(float4*)&A_[i*68 + j0];
            float4 p4 = *(float4*)&prow[j0];
            float4 r;
            r.x = pr ? ((j0+0==kp) ? pv : p4.x*pv) : ((j0+0==kp) ? -fp : a4.x - fp*p4.x);
            r.y = pr ? ((j0+1==kp) ? pv : p4.y*pv) : ((j0+1==kp) ? -fp : a4.y - fp*p4.y);
            r.z = pr ? ((j0+2==kp) ? pv : p4.z*pv) : ((j0+2==kp) ? -fp : a4.z - fp*p4.z);
            r.w = pr ? ((j0+3==kp) ? pv : p4.w*pv) : ((j0+3==kp) ? -fp : a4.w - fp*p4.w);
            *(float4*)&A_[i*68 + j0] = r;
          }
          __syncthreads();
        }
      }

      // ---- t1 = W d ----
      if (tid < 64) {
        float s = 0.f;
        #pragma unroll
        for (int l = 0; l < 16; ++l) {
          float4 a4 = *(float4*)&A_[tid*68 + l*4];
          float4 d4 = *(float4*)&dd_[l*4];
          s += a4.x*d4.x + a4.y*d4.y + a4.z*d4.z + a4.w*d4.w;
        }
        t1_[tid] = s;
      }
      __syncthreads();

      // ---- Yt[m][i] = sum_j (W[i][j] p_j) Mraw[m][j]   (stride 68) ----
      {
        int i = tid & 63, wv = tid >> 6;
        float4 vr[16];
        #pragma unroll
        for (int l = 0; l < 16; ++l) {
          float4 a4 = *(float4*)&A_[i*68 + l*4];
          float4 p4 = *(float4*)&pp_[l*4];
          vr[l].x = a4.x*p4.x; vr[l].y = a4.y*p4.y; vr[l].z = a4.z*p4.z; vr[l].w = a4.w*p4.w;
        }
        for (int m = wv*32; m < wv*32 + 32; ++m) {
          float s = 0.f;
          #pragma unroll
          for (int l = 0; l < 16; ++l) {
            float4 mm = *(float4*)&Mr_[m*64 + l*4];
            s += vr[l].x*mm.x + vr[l].y*mm.y + vr[l].z*mm.z + vr[l].w*mm.w;
          }
          U_[m*68 + i] = s;
        }
      }
      __syncthreads();

      // ---- MP overwrite: M[k][i] *= p_i ----
      {
        float4* M4 = (float4*)Mr_;
        #pragma unroll
        for (int e = 0; e < 8; ++e) {
          int e4 = tid + e * NTHR;            // 2048 float4s
          float4 m4 = M4[e4];
          float4 p4 = *(float4*)&pp_[(e4 & 15) * 4];
          m4.x *= p4.x; m4.y *= p4.y; m4.z *= p4.z; m4.w *= p4.w;
          M4[e4] = m4;
        }
      }
      __syncthreads();

      // ---- P update: P[k][m] = Fv_k Fv_m P + dQ - sum_i MP[k][i] Yt[m][i] ----
      {
        int wv = tid >> 6, lj = tid & 63;
        #pragma unroll
        for (int half = 0; half < 2; ++half) {
          int m = half * 64 + lj;
          float4 yr[16];
          #pragma unroll
          for (int l = 0; l < 16; ++l) yr[l] = *(float4*)&U_[m*68 + l*4];
          float fvm = Fv_[m];
          for (int k = wv*32; k < wv*32 + 32; ++k) {
            float s = 0.f;
            #pragma unroll
            for (int l = 0; l < 16; ++l) {
              float4 mp = *(float4*)&Mr_[k*64 + l*4];
              s += mp.x*yr[l].x + mp.y*yr[l].y + mp.z*yr[l].z + mp.w*yr[l].w;
            }
            float pv = Pg[k*NSTA + m];
            Pg[k*NSTA + m] = Fv_[k]*fvm*pv + ((k == m) ? Qv_[k] : 0.f) - s;
          }
        }
      }
      __syncthreads();

      // ---- y finalize: y = yraw + MP @ t1 ; publish ----
      if (tid < NSTA) {
        float s = pool[L_YL + tid];           // yraw (loaded in gamma, untouched since)
        #pragma unroll
        for (int l = 0; l < 16; ++l) {
          float4 mp = *(float4*)&Mr_[tid*64 + l*4];
          float4 t4 = *(float4*)&t1_[l*4];
          s += mp.x*t4.x + mp.y*t4.y + mp.z*t4.z + mp.w*t4.w;
        }
        ws[W_Y + tid] = s;
        out[(size_t)t * NSTA + tid] = s;
      }
    }
    gsync(bar);
  }
}

extern "C" void kernel_launch(void* const* d_in, const int* in_sizes, int n_in,
                              void* d_out, int out_size, void* d_ws, size_t ws_size,
                              hipStream_t stream) {
  const float* x     = (const float*)d_in[0];
  const float* y0    = (const float*)d_in[1];
  const float* P0    = (const float*)d_in[2];
  const float* H     = (const float*)d_in[3];
  const float* R     = (const float*)d_in[4];
  const float* Tl    = (const float*)d_in[5];
  const float* Tu    = (const float*)d_in[6];
  const float* Wih_m = (const float*)d_in[7];
  const float* Whh_m = (const float*)d_in[8];
  const float* bih_m = (const float*)d_in[9];
  const float* bhh_m = (const float*)d_in[10];
  const float* Wfc_m = (const float*)d_in[11];
  const float* bfc_m = (const float*)d_in[12];
  const float* Wih_f = (const float*)d_in[13];
  const float* Whh_f = (const float*)d_in[14];
  const float* bih_f = (const float*)d_in[15];
  const float* bhh_f = (const float*)d_in[16];
  const float* Wfc_f = (const float*)d_in[17];
  const float* bfc_f = (const float*)d_in[18];
  const float* Wih_q = (const float*)d_in[19];
  const float* Whh_q = (const float*)d_in[20];
  const float* bih_q = (const float*)d_in[21];
  const float* bhh_q = (const float*)d_in[22];
  const float* Wfc_q = (const float*)d_in[23];
  const float* bfc_q = (const float*)d_in[24];
  float* out = (float*)d_out;
  float* ws  = (float*)d_ws;

  hipMemsetAsync(d_ws, 0, 8192, stream);

  hipLaunchKernelGGL(tobit_main, dim3(NBLK), dim3(NTHR), 0, stream,
                     x, y0, P0, H, R, Tl, Tu,
                     Wih_m, Whh_m, bih_m, bhh_m, Wfc_m, bfc_m,
                     Wih_f, Whh_f, bih_f, bhh_f, Wfc_f, bfc_f,
                     Wih_q, Whh_q, bih_q, bhh_q, Wfc_q, bfc_q,
                     out, ws);
}